// Round 14
// baseline (152.978 us; speedup 1.0000x reference)
//
#include <hip/hip_runtime.h>

#define S_LEN 2048
#define HID_DIM 2048
#define NG 8
#define NHQ 4
#define DH 64
// Q pre-scale = ATT_SCALE * log2(e): softmax runs in exp2 domain
#define QSCALE 0.18033688011112042f
#define FIXMAX 12.0f

typedef short short8 __attribute__((ext_vector_type(8)));
typedef float f32x4 __attribute__((ext_vector_type(4)));
typedef unsigned short ushort_t;

__device__ __forceinline__ unsigned short f2bf(float f) {
  unsigned u = __builtin_bit_cast(unsigned, f);
  u += 0x7fffu + ((u >> 16) & 1u);   // RNE
  return (unsigned short)(u >> 16);
}

__device__ __forceinline__ void mfma16(f32x4& d, short8 a, short8 b) {
  asm volatile("v_mfma_f32_16x16x32_bf16 %0, %1, %2, %0" : "+v"(d) : "v"(a), "v"(b));
}

#define GLDS16(gp, lp) __builtin_amdgcn_global_load_lds( \
    (__attribute__((address_space(1))) void*)(gp),       \
    (__attribute__((address_space(3))) void*)(lp), 16, 0, 0)

// ---------------- fp32 -> bf16 convert (vectorized) ----------------
__global__ __launch_bounds__(256) void cvt_bf16_k(const float* __restrict__ in,
                                                  ushort_t* __restrict__ out, int n4) {
  int i = blockIdx.x * 256 + threadIdx.x;
  if (i >= n4) return;
  float4 v = ((const float4*)in)[i];
  ushort4 o;
  o.x = f2bf(v.x); o.y = f2bf(v.y); o.z = f2bf(v.z); o.w = f2bf(v.w);
  ((ushort4*)out)[i] = o;
}

// ---------------- fp32 -> bf16 transpose: out[C][R] = in[R][C]^T ----------------
__global__ __launch_bounds__(256) void tcvt_k(const float* __restrict__ in,
                                              ushort_t* __restrict__ out, int R, int C) {
  __shared__ ushort_t t[32][33];
  int bx = blockIdx.x * 32, by = blockIdx.y * 32;
  int tx = threadIdx.x & 31, ty = threadIdx.x >> 5;
  for (int j = ty; j < 32; j += 8)
    t[j][tx] = f2bf(in[(long)(by + j) * C + bx + tx]);
  __syncthreads();
  for (int j = ty; j < 32; j += 8)
    out[(long)(bx + j) * R + by + tx] = t[tx][j];
}

// ---------------- cos/sin transpose: csT[i][s] = cs[s][i]  (i<32) ----------------
__global__ __launch_bounds__(256) void cs_trans_k(const float* __restrict__ cosb,
                                                  const float* __restrict__ sinb,
                                                  float* __restrict__ cosT,
                                                  float* __restrict__ sinT) {
  int idx = blockIdx.x * 256 + threadIdx.x;   // 65536 total
  int s = idx >> 5, i = idx & 31;             // coalesced reads
  cosT[i * 2048 + s] = cosb[s * 32 + i];
  sinT[i * 2048 + s] = sinb[s * 32 + i];
}

// ======== shared GEMM K-loop pieces: 128x128 tile, BK=64, XOR-swizzled LDS ======
#define GEMM_PROLOG()                                                       \
  const int tid = threadIdx.x;                                              \
  const int w = tid >> 6, lane = tid & 63;                                  \
  const int m0 = blockIdx.y * 128, n0 = blockIdx.x * 128;                   \
  const int sl = lane >> 3;                                                 \
  const int sc = (lane & 7) ^ sl;                                           \
  const ushort_t* Ag = A + (size_t)(m0 + 32 * w + sl) * K + sc * 8;         \
  const ushort_t* Bg = BT + (size_t)(n0 + 32 * w + sl) * K + sc * 8;        \
  f32x4 acc[4][4];                                                          \
  _Pragma("unroll") for (int i = 0; i < 4; ++i)                             \
  _Pragma("unroll") for (int j = 0; j < 4; ++j)                             \
      acc[i][j] = (f32x4){0.f, 0.f, 0.f, 0.f};                              \
  const int fr = lane & 15;                                                 \
  const int kq4 = lane >> 4;                                                \
  const int wm = w >> 1, wn = w & 1;

#define GEMM_KLOOP()                                                        \
  for (int kt = 0; kt < K; kt += 64) {                                      \
    GLDS16(Ag,          &Al[(32 * w) * 64]);                                \
    GLDS16(Ag +  8 * K, &Al[(32 * w + 8) * 64]);                            \
    GLDS16(Ag + 16 * K, &Al[(32 * w + 16) * 64]);                           \
    GLDS16(Ag + 24 * K, &Al[(32 * w + 24) * 64]);                           \
    GLDS16(Bg,          &Bl[(32 * w) * 64]);                                \
    GLDS16(Bg +  8 * K, &Bl[(32 * w + 8) * 64]);                            \
    GLDS16(Bg + 16 * K, &Bl[(32 * w + 16) * 64]);                           \
    GLDS16(Bg + 24 * K, &Bl[(32 * w + 24) * 64]);                           \
    Ag += 64; Bg += 64;                                                     \
    __syncthreads();                                                        \
    _Pragma("unroll")                                                       \
    for (int c = 0; c < 2; ++c) {                                           \
      short8 af[4], bfr[4];                                                 \
      _Pragma("unroll") for (int mf = 0; mf < 4; ++mf) {                    \
        const int row = 64 * wm + 16 * mf + fr;                             \
        af[mf] = *(const short8*)&Al[row * 64 +                             \
                 (((kq4 + 4 * c) ^ (row & 7)) << 3)];                       \
      }                                                                     \
      _Pragma("unroll") for (int nf = 0; nf < 4; ++nf) {                    \
        const int row = 64 * wn + 16 * nf + fr;                             \
        bfr[nf] = *(const short8*)&Bl[row * 64 +                            \
                  (((kq4 + 4 * c) ^ (row & 7)) << 3)];                      \
      }                                                                     \
      _Pragma("unroll") for (int mf = 0; mf < 4; ++mf)                      \
      _Pragma("unroll") for (int nf = 0; nf < 4; ++nf)                      \
          mfma16(acc[mf][nf], af[mf], bfr[nf]);                             \
    }                                                                       \
    __syncthreads();                                                        \
  }

// ---------------- plain GEMM: C(MxN) fp32 = A(MxK) * BT(NxK)^T ----------------
__global__ __launch_bounds__(256) void gemm_bt_k(const ushort_t* __restrict__ A,
                                                 const ushort_t* __restrict__ BT,
                                                 float* __restrict__ C,
                                                 int M, int N, int K) {
  __shared__ __align__(16) ushort_t Al[128 * 64];
  __shared__ __align__(16) ushort_t Bl[128 * 64];
  GEMM_PROLOG();
  GEMM_KLOOP();
  const int crow = m0 + 64 * wm + 4 * (lane >> 4);
  const int ccol = n0 + 64 * wn + fr;
#pragma unroll
  for (int mf = 0; mf < 4; ++mf)
#pragma unroll
    for (int nf = 0; nf < 4; ++nf)
#pragma unroll
      for (int r = 0; r < 4; ++r)
        C[(size_t)(crow + 16 * mf + r) * N + ccol + 16 * nf] = acc[mf][nf][r];
}

// ---------- QKV GEMM with fused RoPE + bf16 + head-major epilogue ----------
__global__ __launch_bounds__(256) void gemm_qkv_k(const ushort_t* __restrict__ A,
                                                  const ushort_t* __restrict__ BT,
                                                  const float* __restrict__ cosT,
                                                  const float* __restrict__ sinT,
                                                  ushort_t* __restrict__ Qbf,
                                                  ushort_t* __restrict__ Kbf,
                                                  ushort_t* __restrict__ Vbuf,
                                                  int M, int N, int K) {
  __shared__ __align__(16) ushort_t Al[128 * 64];
  __shared__ __align__(16) ushort_t Bl[128 * 64];
  GEMM_PROLOG();
  GEMM_KLOOP();
  const int crow = m0 + 64 * wm + 4 * (lane >> 4);
  const int hb = ((n0 % 384) >> 6) + wn;
  const int gg = n0 / 384;
  if (hb == 5) {  // v head: plain bf16, row-major [g][s][64]
    ushort_t* dst = Vbuf + (size_t)gg * 2048 * 64;
#pragma unroll
    for (int mf = 0; mf < 4; ++mf)
#pragma unroll
      for (int nf = 0; nf < 4; ++nf)
#pragma unroll
        for (int r = 0; r < 4; ++r)
          dst[(size_t)(crow + 16 * mf + r) * 64 + 16 * nf + fr] =
              f2bf(acc[mf][nf][r]);
  } else {        // q or k head: fused RoPE (+ QSCALE for q)
    const float qs = (hb < 4) ? QSCALE : 1.0f;
    ushort_t* dst = (hb < 4) ? Qbf + (size_t)(gg * 4 + hb) * 2048 * 64
                             : Kbf + (size_t)gg * 2048 * 64;
#pragma unroll
    for (int mf = 0; mf < 4; ++mf) {
#pragma unroll
      for (int nf2 = 0; nf2 < 2; ++nf2) {
        const int i = 16 * nf2 + fr;
        float4 cT = *(const float4*)&cosT[(size_t)i * 2048 + crow + 16 * mf];
        float4 sT = *(const float4*)&sinT[(size_t)i * 2048 + crow + 16 * mf];
        const float cc[4] = {cT.x, cT.y, cT.z, cT.w};
        const float ss[4] = {sT.x, sT.y, sT.z, sT.w};
#pragma unroll
        for (int r = 0; r < 4; ++r) {
          const size_t row = crow + 16 * mf + r;
          float x1 = acc[mf][nf2][r], x2 = acc[mf][nf2 + 2][r];
          dst[row * 64 + i]      = f2bf((x1 * cc[r] - x2 * ss[r]) * qs);
          dst[row * 64 + i + 32] = f2bf((x2 * cc[r] + x1 * ss[r]) * qs);
        }
      }
    }
  }
}

// ---------------- V transpose (bf16): Vt[g][d][s] = Vbuf[g][s][d] ----------------
__global__ __launch_bounds__(256) void vtrans_k(const ushort_t* __restrict__ Vbuf,
                                                ushort_t* __restrict__ Vt) {
  __shared__ ushort_t t[64][65];
  int s0 = blockIdx.x * 64, g = blockIdx.y;
  for (int idx = threadIdx.x; idx < 4096; idx += 256) {
    int r = idx >> 6, d = idx & 63;
    t[d][r] = Vbuf[((size_t)g * 2048 + s0 + r) * 64 + d];
  }
  __syncthreads();
  for (int idx = threadIdx.x; idx < 4096; idx += 256) {
    int d = idx >> 6, c = idx & 63;
    Vt[((size_t)g * 64 + d) * 2048 + s0 + c] = t[d][c];
  }
}

// ---------------- bf16 MFMA flash attention v12: 2 q-sets / wave, 2-wave blocks ----
// attn9/attn10-verified data path: fixed-max exp2 softmax, ones-MFMA lsum,
// swizzled GLDS staging, counted-vmcnt barriers. Structure: 64 q-rows per
// block, 2 waves x 32 rows (two 16-row sets sharing K/V fragment reads ->
// LDS traffic per FLOP x0.75, 36 MFMA/wave-step). LDS 40KB -> 4 blocks/CU,
// same 1024-block heavy-first u-mapping as attn9.
__global__ __launch_bounds__(128, 2) void attn12_k(const ushort_t* __restrict__ Qbf,
                                                   const ushort_t* __restrict__ Kbf,
                                                   const ushort_t* __restrict__ Vt,
                                                   ushort_t* __restrict__ outb) {
  __shared__ __align__(16) ushort_t Kl[2][64 * 64];
  __shared__ __align__(16) ushort_t Vl[2][64 * 64];
  __shared__ __align__(16) ushort_t Pl[2][2048];   // per wave: 32 rows x 128 B
  const int gh = blockIdx.x;
  const int y = blockIdx.y;
  const int bb = y & 7, aa = y >> 3;
  const int u = (aa == 0) ? 31 - bb : (aa == 1) ? 16 + bb : (aa == 2) ? 15 - bb : bb;
  const int g = gh >> 2;
  const int w = threadIdx.x >> 6, l = threadIdx.x & 63;
  const int li = l & 15, hi = l >> 4;
  const int q0 = 64 * u + 32 * w;          // this wave's 32-row base
  const int nt = u + 1;

  const ushort_t* Qh = Qbf + (size_t)gh * 2048 * 64;
  const ushort_t* Kh = Kbf + (size_t)g * 2048 * 64;
  const ushort_t* Vh = Vt + (size_t)g * 64 * 2048;
  char* Pw = (char*)&Pl[w][0];

  // staging: wave w covers rows [32w, 32w+32) as 4 GLDS units of 8 rows
  const int sr = 32 * w + (l >> 3);        // unit j adds 8j
  const int sc = (l & 7) ^ (l >> 3);
  const short8 ones = {0x3F80, 0x3F80, 0x3F80, 0x3F80, 0x3F80, 0x3F80, 0x3F80, 0x3F80};

  short8 aq00 = *(const short8*)&Qh[(q0 + li) * 64 + hi * 8];
  short8 aq01 = *(const short8*)&Qh[(q0 + li) * 64 + 32 + hi * 8];
  short8 aq10 = *(const short8*)&Qh[(q0 + 16 + li) * 64 + hi * 8];
  short8 aq11 = *(const short8*)&Qh[(q0 + 16 + li) * 64 + 32 + hi * 8];

  f32x4 o0[4], o1[4];
#pragma unroll
  for (int df = 0; df < 4; ++df) {
    o0[df] = (f32x4){0.f, 0.f, 0.f, 0.f};
    o1[df] = (f32x4){0.f, 0.f, 0.f, 0.f};
  }
  f32x4 os0 = (f32x4){0.f, 0.f, 0.f, 0.f};
  f32x4 os1 = (f32x4){0.f, 0.f, 0.f, 0.f};

#define STAGE_TILE(B, TN)                                                     \
  {                                                                           \
    _Pragma("unroll")                                                         \
    for (int j = 0; j < 4; ++j) {                                             \
      GLDS16(Kh + (size_t)((TN) + sr + 8 * j) * 64 + sc * 8,                  \
             &Kl[B][(32 * w + 8 * j) * 64]);                                  \
      GLDS16(Vh + (size_t)(sr + 8 * j) * 2048 + (TN) + sc * 8,                \
             &Vl[B][(32 * w + 8 * j) * 64]);                                  \
    }                                                                         \
  }

  // prologue: stage tile 0 into buf 0 (completion enforced by step-0 vmcnt)
  STAGE_TILE(0, 0);

  int buf = 0;
  for (int it = 0; it < nt; ++it) {
    const int t0 = it * 64;
    const bool pf = (it + 1 < nt);
    if (pf) STAGE_TILE(buf ^ 1, t0 + 64);  // 8 loads stay in flight
    if (pf) asm volatile("s_waitcnt vmcnt(8)" ::: "memory");
    else    asm volatile("s_waitcnt vmcnt(0)" ::: "memory");
    __builtin_amdgcn_sched_barrier(0);
    __builtin_amdgcn_s_barrier();
    __builtin_amdgcn_sched_barrier(0);

    const ushort_t* kb = &Kl[buf][0];
    const ushort_t* vb = &Vl[buf][0];

    // ---- QK^T: both sets share the 8 K-frag reads ----
    f32x4 sf0[4], sf1[4];
#pragma unroll
    for (int f = 0; f < 4; ++f) {
      sf0[f] = (f32x4){0.f, 0.f, 0.f, 0.f};
      sf1[f] = (f32x4){0.f, 0.f, 0.f, 0.f};
    }
    __builtin_amdgcn_s_setprio(1);
#pragma unroll
    for (int f = 0; f < 4; ++f) {
      const int row = 16 * f + li;
      short8 b0 = *(const short8*)&kb[row * 64 + ((hi ^ (row & 7)) << 3)];
      short8 b1 = *(const short8*)&kb[row * 64 + (((hi + 4) ^ (row & 7)) << 3)];
      mfma16(sf0[f], aq00, b0);
      mfma16(sf0[f], aq01, b1);
      mfma16(sf1[f], aq10, b0);
      mfma16(sf1[f], aq11, b1);
    }
    __builtin_amdgcn_s_setprio(0);

    // ---- causal mask (diagonal tile only: t0+63 > q0) ----
    if (t0 + 63 > q0) {
#pragma unroll
      for (int f = 0; f < 4; ++f) {
        int t = t0 + 16 * f + li;
#pragma unroll
        for (int r = 0; r < 4; ++r) {
          if (t > q0 + 4 * hi + r) sf0[f][r] = -1e30f;
          if (t > q0 + 16 + 4 * hi + r) sf1[f][r] = -1e30f;
        }
      }
    }
    // ---- fixed-max softmax: P = exp2(S' - 12), truncate-store to bf16 ----
#pragma unroll
    for (int f = 0; f < 4; ++f) {
      int k2 = 2 * (li + 16 * f);
#pragma unroll
      for (int r = 0; r < 4; ++r) {
        float p0 = __builtin_amdgcn_exp2f(sf0[f][r] - FIXMAX);
        float p1 = __builtin_amdgcn_exp2f(sf1[f][r] - FIXMAX);
        int q = 4 * hi + r;
        *(ushort_t*)(Pw + q * 128 + (k2 ^ ((q & 7) << 4))) =
            (ushort_t)(__builtin_bit_cast(unsigned, p0) >> 16);
        *(ushort_t*)(Pw + (q + 16) * 128 + (k2 ^ ((q & 7) << 4))) =
            (ushort_t)(__builtin_bit_cast(unsigned, p1) >> 16);
      }
    }

    // ---- PV: both sets share the 8 V-frag reads; lsum via ones-MFMA ----
    __builtin_amdgcn_s_setprio(1);
#pragma unroll
    for (int kst = 0; kst < 2; ++kst) {
      const int pb = (((4 * kst + hi) ^ (li & 7)) << 4);
      short8 pa0 = *(const short8*)(Pw + li * 128 + pb);
      short8 pa1 = *(const short8*)(Pw + (li + 16) * 128 + pb);
#pragma unroll
      for (int df = 0; df < 4; ++df) {
        const int row = 16 * df + li;
        short8 bv = *(const short8*)&vb[row * 64 + (((4 * kst + hi) ^ (row & 7)) << 3)];
        mfma16(o0[df], pa0, bv);
        mfma16(o1[df], pa1, bv);
      }
      mfma16(os0, pa0, ones);
      mfma16(os1, pa1, ones);
    }
    __builtin_amdgcn_s_setprio(0);

    // closing barrier: all waves done reading buf
    __builtin_amdgcn_sched_barrier(0);
    __builtin_amdgcn_s_barrier();
    __builtin_amdgcn_sched_barrier(0);
    buf ^= 1;
  }
#undef STAGE_TILE
  // ---- epilogue: normalize by ones-MFMA row-sums, store bf16 (RNE) ----
#pragma unroll
  for (int r = 0; r < 4; ++r) {
    float inv0 = 1.f / os0[r];
    float inv1 = 1.f / os1[r];
#pragma unroll
    for (int df = 0; df < 4; ++df) {
      outb[(size_t)(q0 + 4 * hi + r) * HID_DIM + gh * 64 + 16 * df + li] =
          f2bf(o0[df][r] * inv0);
      outb[(size_t)(q0 + 16 + 4 * hi + r) * HID_DIM + gh * 64 + 16 * df + li] =
          f2bf(o1[df][r] * inv1);
    }
  }
}

extern "C" void kernel_launch(void* const* d_in, const int* in_sizes, int n_in,
                              void* d_out, int out_size, void* d_ws, size_t ws_size,
                              hipStream_t stream) {
  const float* X    = (const float*)d_in[0];  // 2048x2048
  const float* cosb = (const float*)d_in[1];  // 2048x32
  const float* sinb = (const float*)d_in[2];  // 2048x32
  const float* Wqkv = (const float*)d_in[3];  // 2048x3072
  const float* Wd   = (const float*)d_in[4];  // 2048x2048
  float* out = (float*)d_out;                 // 2048x2048 fp32

  // workspace (all disjoint, ~51 MB)
  char* ws = (char*)d_ws;
  ushort_t* Xbf   = (ushort_t*)ws;                             // 8 MB
  ushort_t* WqkvT = Xbf + (size_t)2048 * 2048;                 // 12.6 MB
  ushort_t* WdT   = WqkvT + (size_t)3072 * 2048;               // 8 MB
  ushort_t* Qbf   = WdT + (size_t)2048 * 2048;                 // 8 MB
  ushort_t* Kbf   = Qbf + (size_t)32 * 2048 * 64;              // 2 MB
  ushort_t* Vbuf  = Kbf + (size_t)8 * 2048 * 64;               // 2 MB
  ushort_t* Vt    = Vbuf + (size_t)8 * 2048 * 64;              // 2 MB
  ushort_t* attnO = Vt + (size_t)8 * 2048 * 64;                // 8 MB
  float*    cosT  = (float*)(attnO + (size_t)2048 * 2048);     // 0.25 MB
  float*    sinT  = cosT + (size_t)32 * 2048;                  // 0.25 MB

  cvt_bf16_k<<<4096, 256, 0, stream>>>(X, Xbf, (2048 * 2048) / 4);
  tcvt_k<<<dim3(3072 / 32, 2048 / 32), 256, 0, stream>>>(Wqkv, WqkvT, 2048, 3072);
  tcvt_k<<<dim3(2048 / 32, 2048 / 32), 256, 0, stream>>>(Wd, WdT, 2048, 2048);
  cs_trans_k<<<256, 256, 0, stream>>>(cosb, sinb, cosT, sinT);

  // qkv GEMM (M=2048, N=3072, K=2048) with fused RoPE/bf16/head-major epilogue
  gemm_qkv_k<<<dim3(3072 / 128, 2048 / 128), 256, 0, stream>>>(
      Xbf, WqkvT, cosT, sinT, Qbf, Kbf, Vbuf, 2048, 3072, 2048);

  vtrans_k<<<dim3(S_LEN / 64, NG), 256, 0, stream>>>(Vbuf, Vt);

  attn12_k<<<dim3(NG * NHQ, 32), 128, 0, stream>>>(Qbf, Kbf, Vt, attnO);

  // out = attnO @ Wd  (M=2048, N=2048, K=2048)
  gemm_bt_k<<<dim3(2048 / 128, 2048 / 128), 256, 0, stream>>>(attnO, WdT, out,
                                                              2048, 2048, 2048);
}

// Round 15
// 138.538 us; speedup vs baseline: 1.1042x; 1.1042x over previous
//
#include <hip/hip_runtime.h>

#define S_LEN 2048
#define HID_DIM 2048
#define NG 8
#define NHQ 4
#define DH 64
// Q pre-scale = ATT_SCALE * log2(e): softmax runs in exp2 domain
#define QSCALE 0.18033688011112042f
#define FIXMAX 12.0f

typedef short short8 __attribute__((ext_vector_type(8)));
typedef float f32x4 __attribute__((ext_vector_type(4)));
typedef unsigned short ushort_t;

__device__ __forceinline__ unsigned short f2bf(float f) {
  unsigned u = __builtin_bit_cast(unsigned, f);
  u += 0x7fffu + ((u >> 16) & 1u);   // RNE
  return (unsigned short)(u >> 16);
}

__device__ __forceinline__ void mfma16(f32x4& d, short8 a, short8 b) {
  asm volatile("v_mfma_f32_16x16x32_bf16 %0, %1, %2, %0" : "+v"(d) : "v"(a), "v"(b));
}

#define GLDS16(gp, lp) __builtin_amdgcn_global_load_lds( \
    (__attribute__((address_space(1))) void*)(gp),       \
    (__attribute__((address_space(3))) void*)(lp), 16, 0, 0)

// ---------------- fp32 -> bf16 convert (vectorized) ----------------
__global__ __launch_bounds__(256) void cvt_bf16_k(const float* __restrict__ in,
                                                  ushort_t* __restrict__ out, int n4) {
  int i = blockIdx.x * 256 + threadIdx.x;
  if (i >= n4) return;
  float4 v = ((const float4*)in)[i];
  ushort4 o;
  o.x = f2bf(v.x); o.y = f2bf(v.y); o.z = f2bf(v.z); o.w = f2bf(v.w);
  ((ushort4*)out)[i] = o;
}

// ---------------- fp32 -> bf16 transpose: out[C][R] = in[R][C]^T ----------------
__global__ __launch_bounds__(256) void tcvt_k(const float* __restrict__ in,
                                              ushort_t* __restrict__ out, int R, int C) {
  __shared__ ushort_t t[32][33];
  int bx = blockIdx.x * 32, by = blockIdx.y * 32;
  int tx = threadIdx.x & 31, ty = threadIdx.x >> 5;
  for (int j = ty; j < 32; j += 8)
    t[j][tx] = f2bf(in[(long)(by + j) * C + bx + tx]);
  __syncthreads();
  for (int j = ty; j < 32; j += 8)
    out[(long)(bx + j) * R + by + tx] = t[tx][j];
}

// ---------------- cos/sin transpose: csT[i][s] = cs[s][i]  (i<32) ----------------
__global__ __launch_bounds__(256) void cs_trans_k(const float* __restrict__ cosb,
                                                  const float* __restrict__ sinb,
                                                  float* __restrict__ cosT,
                                                  float* __restrict__ sinT) {
  int idx = blockIdx.x * 256 + threadIdx.x;   // 65536 total
  int s = idx >> 5, i = idx & 31;             // coalesced reads
  cosT[i * 2048 + s] = cosb[s * 32 + i];
  sinT[i * 2048 + s] = sinb[s * 32 + i];
}

// ==== shared GEMM pieces: 128x64 tile, BK=64, 4 waves (4M x 1N), XOR swizzle ====
// Grid doubles vs 128x128 (dense: 512 blocks = 2/CU, qkv: 768 = 3/CU) so the
// 2-barrier loop gets cross-block overlap. LDS 24KB -> up to 6 blocks/CU.
// Wave w: A rows [32w,32w+32) (4 GLDS units), B rows [16w,16w+16) (2 units);
// lane: unit-row sl=lane>>3, global chunk sc=(lane&7)^sl (LDS linear).
// ds_read chunk: (kq4+4c) ^ (row&7) — write/read XOR identical (row&7==sl).
#define GEMM_PROLOG64()                                                     \
  const int tid = threadIdx.x;                                              \
  const int w = tid >> 6, lane = tid & 63;                                  \
  const int m0 = blockIdx.y * 128, n0 = blockIdx.x * 64;                    \
  const int sl = lane >> 3;                                                 \
  const int sc = (lane & 7) ^ sl;                                           \
  const ushort_t* Ag = A + (size_t)(m0 + 32 * w + sl) * K + sc * 8;         \
  const ushort_t* Bg = BT + (size_t)(n0 + 16 * w + sl) * K + sc * 8;        \
  f32x4 acc[2][4];                                                          \
  _Pragma("unroll") for (int i = 0; i < 2; ++i)                             \
  _Pragma("unroll") for (int j = 0; j < 4; ++j)                             \
      acc[i][j] = (f32x4){0.f, 0.f, 0.f, 0.f};                              \
  const int fr = lane & 15;                                                 \
  const int kq4 = lane >> 4;

#define GEMM_KLOOP64()                                                     \
  for (int kt = 0; kt < K; kt += 64) {                                     \
    GLDS16(Ag,          &Al[(32 * w) * 64]);                               \
    GLDS16(Ag +  8 * K, &Al[(32 * w + 8) * 64]);                           \
    GLDS16(Ag + 16 * K, &Al[(32 * w + 16) * 64]);                          \
    GLDS16(Ag + 24 * K, &Al[(32 * w + 24) * 64]);                          \
    GLDS16(Bg,          &Bl[(16 * w) * 64]);                               \
    GLDS16(Bg +  8 * K, &Bl[(16 * w + 8) * 64]);                           \
    Ag += 64; Bg += 64;                                                    \
    __syncthreads();                                                       \
    _Pragma("unroll")                                                      \
    for (int c = 0; c < 2; ++c) {                                          \
      short8 af[2], bfr[4];                                                \
      _Pragma("unroll") for (int mf = 0; mf < 2; ++mf) {                   \
        const int row = 32 * w + 16 * mf + fr;                             \
        af[mf] = *(const short8*)&Al[row * 64 +                            \
                 (((kq4 + 4 * c) ^ (row & 7)) << 3)];                      \
      }                                                                    \
      _Pragma("unroll") for (int nf = 0; nf < 4; ++nf) {                   \
        const int row = 16 * nf + fr;                                      \
        bfr[nf] = *(const short8*)&Bl[row * 64 +                           \
                  (((kq4 + 4 * c) ^ (row & 7)) << 3)];                     \
      }                                                                    \
      _Pragma("unroll") for (int mf = 0; mf < 2; ++mf)                     \
      _Pragma("unroll") for (int nf = 0; nf < 4; ++nf)                     \
          mfma16(acc[mf][nf], af[mf], bfr[nf]);                            \
    }                                                                      \
    __syncthreads();                                                       \
  }

// ---------------- plain GEMM: C(MxN) fp32 = A(MxK) * BT(NxK)^T ----------------
__global__ __launch_bounds__(256) void gemm_bt_k(const ushort_t* __restrict__ A,
                                                 const ushort_t* __restrict__ BT,
                                                 float* __restrict__ C,
                                                 int M, int N, int K) {
  __shared__ __align__(16) ushort_t Al[128 * 64];
  __shared__ __align__(16) ushort_t Bl[64 * 64];
  GEMM_PROLOG64();
  GEMM_KLOOP64();
  const int crow = m0 + 32 * w + 4 * (lane >> 4);
  const int ccol = n0 + fr;
#pragma unroll
  for (int mf = 0; mf < 2; ++mf)
#pragma unroll
    for (int nf = 0; nf < 4; ++nf)
#pragma unroll
      for (int r = 0; r < 4; ++r)
        C[(size_t)(crow + 16 * mf + r) * N + ccol + 16 * nf] = acc[mf][nf][r];
}

// ---------- QKV GEMM with fused RoPE + bf16 + head-major epilogue ----------
// Block n-span = 64 = exactly one head: hb = bx%6 (0..3=q, 4=k, 5=v), gg = bx/6.
// RoPE pair (i, i+32) lives in acc[mf][nf2] / acc[mf][nf2+2] of the same thread.
__global__ __launch_bounds__(256) void gemm_qkv_k(const ushort_t* __restrict__ A,
                                                  const ushort_t* __restrict__ BT,
                                                  const float* __restrict__ cosT,
                                                  const float* __restrict__ sinT,
                                                  ushort_t* __restrict__ Qbf,
                                                  ushort_t* __restrict__ Kbf,
                                                  ushort_t* __restrict__ Vbuf,
                                                  int M, int N, int K) {
  __shared__ __align__(16) ushort_t Al[128 * 64];
  __shared__ __align__(16) ushort_t Bl[64 * 64];
  GEMM_PROLOG64();
  GEMM_KLOOP64();
  const int crow = m0 + 32 * w + 4 * (lane >> 4);
  const int hb = blockIdx.x % 6;
  const int gg = blockIdx.x / 6;
  if (hb == 5) {  // v head: plain bf16, row-major [g][s][64]
    ushort_t* dst = Vbuf + (size_t)gg * 2048 * 64;
#pragma unroll
    for (int mf = 0; mf < 2; ++mf)
#pragma unroll
      for (int nf = 0; nf < 4; ++nf)
#pragma unroll
        for (int r = 0; r < 4; ++r)
          dst[(size_t)(crow + 16 * mf + r) * 64 + 16 * nf + fr] =
              f2bf(acc[mf][nf][r]);
  } else {        // q or k head: fused RoPE (+ QSCALE for q)
    const float qs = (hb < 4) ? QSCALE : 1.0f;
    ushort_t* dst = (hb < 4) ? Qbf + (size_t)(gg * 4 + hb) * 2048 * 64
                             : Kbf + (size_t)gg * 2048 * 64;
#pragma unroll
    for (int mf = 0; mf < 2; ++mf) {
#pragma unroll
      for (int nf2 = 0; nf2 < 2; ++nf2) {
        const int i = 16 * nf2 + fr;
        float4 cT = *(const float4*)&cosT[(size_t)i * 2048 + crow + 16 * mf];
        float4 sT = *(const float4*)&sinT[(size_t)i * 2048 + crow + 16 * mf];
        const float cc[4] = {cT.x, cT.y, cT.z, cT.w};
        const float ss[4] = {sT.x, sT.y, sT.z, sT.w};
#pragma unroll
        for (int r = 0; r < 4; ++r) {
          const size_t row = crow + 16 * mf + r;
          float x1 = acc[mf][nf2][r], x2 = acc[mf][nf2 + 2][r];
          dst[row * 64 + i]      = f2bf((x1 * cc[r] - x2 * ss[r]) * qs);
          dst[row * 64 + i + 32] = f2bf((x2 * cc[r] + x1 * ss[r]) * qs);
        }
      }
    }
  }
}

// ---------------- V transpose (bf16): Vt[g][d][s] = Vbuf[g][s][d] ----------------
__global__ __launch_bounds__(256) void vtrans_k(const ushort_t* __restrict__ Vbuf,
                                                ushort_t* __restrict__ Vt) {
  __shared__ ushort_t t[64][65];
  int s0 = blockIdx.x * 64, g = blockIdx.y;
  for (int idx = threadIdx.x; idx < 4096; idx += 256) {
    int r = idx >> 6, d = idx & 63;
    t[d][r] = Vbuf[((size_t)g * 2048 + s0 + r) * 64 + d];
  }
  __syncthreads();
  for (int idx = threadIdx.x; idx < 4096; idx += 256) {
    int d = idx >> 6, c = idx & 63;
    Vt[((size_t)g * 64 + d) * 2048 + s0 + c] = t[d][c];
  }
}

// ---------------- bf16 MFMA flash attention v9 (round-10-verified, 44.4 us) ----
// Fixed-max exp2 softmax; ones-MFMA lsum (same bf16 P as PV -> bias cancels);
// swizzled GLDS staging; 4 waves x 16 q-rows; grid 32x32; 4 blocks/CU.
__global__ __launch_bounds__(256, 4) void attn9_k(const ushort_t* __restrict__ Qbf,
                                                  const ushort_t* __restrict__ Kbf,
                                                  const ushort_t* __restrict__ Vt,
                                                  ushort_t* __restrict__ outb) {
  __shared__ __align__(16) ushort_t Kl[2][64 * 64];
  __shared__ __align__(16) ushort_t Vl[2][64 * 64];
  __shared__ __align__(16) ushort_t Pl[4][1024];
  const int gh = blockIdx.x;
  const int y = blockIdx.y;
  const int bb = y & 7, aa = y >> 3;
  const int u = (aa == 0) ? 31 - bb : (aa == 1) ? 16 + bb : (aa == 2) ? 15 - bb : bb;
  const int g = gh >> 2;
  const int w = threadIdx.x >> 6, l = threadIdx.x & 63;
  const int li = l & 15, hi = l >> 4;
  const int q0 = 64 * u + 16 * w;
  const int nt = u + 1;

  const ushort_t* Qh = Qbf + (long)gh * 2048 * 64;
  const ushort_t* Kh = Kbf + (long)g * 2048 * 64;
  const ushort_t* Vh = Vt + (long)g * 64 * 2048;
  char* Pw = (char*)&Pl[w][0];

  const int sr = 16 * w + (l >> 3);
  const int sc = (l & 7) ^ (l >> 3);
  const short8 ones = {0x3F80, 0x3F80, 0x3F80, 0x3F80, 0x3F80, 0x3F80, 0x3F80, 0x3F80};

  short8 aq0 = *(const short8*)&Qh[(q0 + li) * 64 + hi * 8];
  short8 aq1 = *(const short8*)&Qh[(q0 + li) * 64 + 32 + hi * 8];

  f32x4 o[4];
#pragma unroll
  for (int df = 0; df < 4; ++df) o[df] = (f32x4){0.f, 0.f, 0.f, 0.f};
  f32x4 os = (f32x4){0.f, 0.f, 0.f, 0.f};   // row-sums via ones-column MFMA

  // prologue: stage tile 0 into buf 0
  GLDS16(Kh + (long)sr * 64 + sc * 8,         &Kl[0][(16 * w) * 64]);
  GLDS16(Kh + (long)(sr + 8) * 64 + sc * 8,   &Kl[0][(16 * w + 8) * 64]);
  GLDS16(Vh + (long)sr * 2048 + sc * 8,       &Vl[0][(16 * w) * 64]);
  GLDS16(Vh + (long)(sr + 8) * 2048 + sc * 8, &Vl[0][(16 * w + 8) * 64]);
  __syncthreads();

  int buf = 0;
  for (int it = 0; it < nt; ++it) {
    const int t0 = it * 64;
    if (it + 1 < nt) {  // prefetch next tile into buf^1 (stays in flight)
      const int tn = t0 + 64;
      GLDS16(Kh + (long)(tn + sr) * 64 + sc * 8,       &Kl[buf ^ 1][(16 * w) * 64]);
      GLDS16(Kh + (long)(tn + sr + 8) * 64 + sc * 8,   &Kl[buf ^ 1][(16 * w + 8) * 64]);
      GLDS16(Vh + (long)sr * 2048 + tn + sc * 8,       &Vl[buf ^ 1][(16 * w) * 64]);
      GLDS16(Vh + (long)(sr + 8) * 2048 + tn + sc * 8, &Vl[buf ^ 1][(16 * w + 8) * 64]);
    }
    const ushort_t* kb = &Kl[buf][0];
    const ushort_t* vb = &Vl[buf][0];

    // ---- QK^T: S'[16q][64t] (log2 domain) ----
    f32x4 sf[4];
#pragma unroll
    for (int f = 0; f < 4; ++f) sf[f] = (f32x4){0.f, 0.f, 0.f, 0.f};
    __builtin_amdgcn_s_setprio(1);
#pragma unroll
    for (int f = 0; f < 4; ++f) {
      const int row = 16 * f + li;
      short8 b0 = *(const short8*)&kb[row * 64 + ((hi ^ (row & 7)) << 3)];
      short8 b1 = *(const short8*)&kb[row * 64 + (((hi + 4) ^ (row & 7)) << 3)];
      mfma16(sf[f], aq0, b0);
      mfma16(sf[f], aq1, b1);
    }
    __builtin_amdgcn_s_setprio(0);

    // ---- causal mask (diagonal tile only) ----
    if (t0 + 63 > q0) {
#pragma unroll
      for (int f = 0; f < 4; ++f) {
        int t = t0 + 16 * f + li;
#pragma unroll
        for (int r = 0; r < 4; ++r)
          if (t > q0 + 4 * hi + r) sf[f][r] = -1e30f;
      }
    }
    // ---- fixed-max softmax: P = exp2(S' - 12), truncate-store to bf16 ----
#pragma unroll
    for (int f = 0; f < 4; ++f) {
      int k2 = 2 * (li + 16 * f);
#pragma unroll
      for (int r = 0; r < 4; ++r) {
        float p = __builtin_amdgcn_exp2f(sf[f][r] - FIXMAX);
        int q = 4 * hi + r;
        *(ushort_t*)(Pw + q * 128 + (k2 ^ ((q & 7) << 4))) =
            (ushort_t)(__builtin_bit_cast(unsigned, p) >> 16);
      }
    }

    // ---- PV: O[16q][64d] += P * V^T; row-sums accumulate via ones-frag ----
    __builtin_amdgcn_s_setprio(1);
#pragma unroll
    for (int kst = 0; kst < 2; ++kst) {
      short8 pa = *(const short8*)(Pw + li * 128 + (((4 * kst + hi) ^ (li & 7)) << 4));
#pragma unroll
      for (int df = 0; df < 4; ++df) {
        const int row = 16 * df + li;
        short8 bv = *(const short8*)&vb[row * 64 + (((4 * kst + hi) ^ (row & 7)) << 3)];
        mfma16(o[df], pa, bv);
      }
      mfma16(os, pa, ones);
    }
    __builtin_amdgcn_s_setprio(0);

    __syncthreads();  // drains GLDS (vmcnt) + all waves done reading buf
    buf ^= 1;
  }
  // ---- epilogue: normalize by ones-MFMA row-sums, store bf16 (RNE) ----
#pragma unroll
  for (int r = 0; r < 4; ++r) {
    float inv = 1.f / os[r];
#pragma unroll
    for (int df = 0; df < 4; ++df)
      outb[(long)(q0 + 4 * hi + r) * HID_DIM + gh * 64 + 16 * df + li] =
          f2bf(o[df][r] * inv);
  }
}

extern "C" void kernel_launch(void* const* d_in, const int* in_sizes, int n_in,
                              void* d_out, int out_size, void* d_ws, size_t ws_size,
                              hipStream_t stream) {
  const float* X    = (const float*)d_in[0];  // 2048x2048
  const float* cosb = (const float*)d_in[1];  // 2048x32
  const float* sinb = (const float*)d_in[2];  // 2048x32
  const float* Wqkv = (const float*)d_in[3];  // 2048x3072
  const float* Wd   = (const float*)d_in[4];  // 2048x2048
  float* out = (float*)d_out;                 // 2048x2048 fp32

  // workspace (all disjoint, ~51 MB)
  char* ws = (char*)d_ws;
  ushort_t* Xbf   = (ushort_t*)ws;                             // 8 MB
  ushort_t* WqkvT = Xbf + (size_t)2048 * 2048;                 // 12.6 MB
  ushort_t* WdT   = WqkvT + (size_t)3072 * 2048;               // 8 MB
  ushort_t* Qbf   = WdT + (size_t)2048 * 2048;                 // 8 MB
  ushort_t* Kbf   = Qbf + (size_t)32 * 2048 * 64;              // 2 MB
  ushort_t* Vbuf  = Kbf + (size_t)8 * 2048 * 64;               // 2 MB
  ushort_t* Vt    = Vbuf + (size_t)8 * 2048 * 64;              // 2 MB
  ushort_t* attnO = Vt + (size_t)8 * 2048 * 64;                // 8 MB
  float*    cosT  = (float*)(attnO + (size_t)2048 * 2048);     // 0.25 MB
  float*    sinT  = cosT + (size_t)32 * 2048;                  // 0.25 MB

  cvt_bf16_k<<<4096, 256, 0, stream>>>(X, Xbf, (2048 * 2048) / 4);
  tcvt_k<<<dim3(3072 / 32, 2048 / 32), 256, 0, stream>>>(Wqkv, WqkvT, 2048, 3072);
  tcvt_k<<<dim3(2048 / 32, 2048 / 32), 256, 0, stream>>>(Wd, WdT, 2048, 2048);
  cs_trans_k<<<256, 256, 0, stream>>>(cosb, sinb, cosT, sinT);

  // qkv GEMM (M=2048, N=3072, K=2048), 128x64 tiles, fused RoPE/bf16 epilogue
  gemm_qkv_k<<<dim3(3072 / 64, 2048 / 128), 256, 0, stream>>>(
      Xbf, WqkvT, cosT, sinT, Qbf, Kbf, Vbuf, 2048, 3072, 2048);

  vtrans_k<<<dim3(S_LEN / 64, NG), 256, 0, stream>>>(Vbuf, Vt);

  attn9_k<<<dim3(NG * NHQ, 32), 256, 0, stream>>>(Qbf, Kbf, Vt, attnO);

  // out = attnO @ Wd  (M=2048, N=2048, K=2048), 128x64 tiles
  gemm_bt_k<<<dim3(2048 / 64, 2048 / 128), 256, 0, stream>>>(attnO, WdT, out,
                                                             2048, 2048, 2048);
}

// Round 16
// 127.837 us; speedup vs baseline: 1.1967x; 1.0837x over previous
//
#include <hip/hip_runtime.h>

#define S_LEN 2048
#define HID_DIM 2048
#define NG 8
#define NHQ 4
#define DH 64
// Q pre-scale = ATT_SCALE * log2(e): softmax runs in exp2 domain
#define QSCALE 0.18033688011112042f
#define FIXMAX 12.0f

typedef short short8 __attribute__((ext_vector_type(8)));
typedef float f32x4 __attribute__((ext_vector_type(4)));
typedef unsigned short ushort_t;

__device__ __forceinline__ unsigned short f2bf(float f) {
  unsigned u = __builtin_bit_cast(unsigned, f);
  u += 0x7fffu + ((u >> 16) & 1u);   // RNE
  return (unsigned short)(u >> 16);
}

__device__ __forceinline__ void mfma16(f32x4& d, short8 a, short8 b) {
  asm volatile("v_mfma_f32_16x16x32_bf16 %0, %1, %2, %0" : "+v"(d) : "v"(a), "v"(b));
}

#define GLDS16(gp, lp) __builtin_amdgcn_global_load_lds( \
    (__attribute__((address_space(1))) void*)(gp),       \
    (__attribute__((address_space(3))) void*)(lp), 16, 0, 0)

// ---------------- fused prep: cvt(X) | tcvt(Wqkv) | tcvt(Wd) | cs_trans ----------
// One launch replaces 4 (removes 3 serial launch gaps + kernel tails).
// Block ranges: [0,4096) cvt, [4096,10240) tcvt Wqkv (96x64),
//               [10240,14336) tcvt Wd (64x64), [14336,14592) cs_trans.
__global__ __launch_bounds__(256) void prep_k(const float* __restrict__ X,
                                              const float* __restrict__ Wqkv,
                                              const float* __restrict__ Wd,
                                              const float* __restrict__ cosb,
                                              const float* __restrict__ sinb,
                                              ushort_t* __restrict__ Xbf,
                                              ushort_t* __restrict__ WqkvT,
                                              ushort_t* __restrict__ WdT,
                                              float* __restrict__ cosT,
                                              float* __restrict__ sinT) {
  __shared__ ushort_t t[32][33];
  const int b = blockIdx.x;
  if (b < 4096) {                       // ---- cvt_bf16: X -> Xbf ----
    int i = b * 256 + threadIdx.x;      // n4 = 2048*2048/4 = 1048576 = 4096*256
    float4 v = ((const float4*)X)[i];
    ushort4 o;
    o.x = f2bf(v.x); o.y = f2bf(v.y); o.z = f2bf(v.z); o.w = f2bf(v.w);
    ((ushort4*)Xbf)[i] = o;
  } else if (b < 14336) {               // ---- tcvt: W -> W^T bf16 ----
    const float* in;
    ushort_t* out;
    int R, C, bx, by;
    if (b < 10240) {
      int idx = b - 4096;               // Wqkv: R=2048, C=3072, grid 96x64
      in = Wqkv; out = WqkvT; R = 2048; C = 3072;
      bx = (idx % 96) * 32; by = (idx / 96) * 32;
    } else {
      int idx = b - 10240;              // Wd: R=2048, C=2048, grid 64x64
      in = Wd; out = WdT; R = 2048; C = 2048;
      bx = (idx % 64) * 32; by = (idx / 64) * 32;
    }
    int tx = threadIdx.x & 31, ty = threadIdx.x >> 5;
    for (int j = ty; j < 32; j += 8)
      t[j][tx] = f2bf(in[(size_t)(by + j) * C + bx + tx]);
    __syncthreads();
    for (int j = ty; j < 32; j += 8)
      out[(size_t)(bx + j) * R + by + tx] = t[tx][j];
  } else {                              // ---- cs_trans: csT[i][s] = cs[s][i] ----
    int idx = (b - 14336) * 256 + threadIdx.x;   // 65536 total
    int s = idx >> 5, i = idx & 31;
    cosT[i * 2048 + s] = cosb[s * 32 + i];
    sinT[i * 2048 + s] = sinb[s * 32 + i];
  }
}

// ==== shared GEMM pieces: 128x64 tile, BK=64, 4 waves (4M x 1N), XOR swizzle ====
#define GEMM_PROLOG64()                                                     \
  const int tid = threadIdx.x;                                              \
  const int w = tid >> 6, lane = tid & 63;                                  \
  const int m0 = blockIdx.y * 128, n0 = blockIdx.x * 64;                    \
  const int sl = lane >> 3;                                                 \
  const int sc = (lane & 7) ^ sl;                                           \
  const ushort_t* Ag = A + (size_t)(m0 + 32 * w + sl) * K + sc * 8;         \
  const ushort_t* Bg = BT + (size_t)(n0 + 16 * w + sl) * K + sc * 8;        \
  f32x4 acc[2][4];                                                          \
  _Pragma("unroll") for (int i = 0; i < 2; ++i)                             \
  _Pragma("unroll") for (int j = 0; j < 4; ++j)                             \
      acc[i][j] = (f32x4){0.f, 0.f, 0.f, 0.f};                              \
  const int fr = lane & 15;                                                 \
  const int kq4 = lane >> 4;

#define GEMM_KLOOP64()                                                     \
  for (int kt = 0; kt < K; kt += 64) {                                     \
    GLDS16(Ag,          &Al[(32 * w) * 64]);                               \
    GLDS16(Ag +  8 * K, &Al[(32 * w + 8) * 64]);                           \
    GLDS16(Ag + 16 * K, &Al[(32 * w + 16) * 64]);                          \
    GLDS16(Ag + 24 * K, &Al[(32 * w + 24) * 64]);                          \
    GLDS16(Bg,          &Bl[(16 * w) * 64]);                               \
    GLDS16(Bg +  8 * K, &Bl[(16 * w + 8) * 64]);                           \
    Ag += 64; Bg += 64;                                                    \
    __syncthreads();                                                       \
    _Pragma("unroll")                                                      \
    for (int c = 0; c < 2; ++c) {                                          \
      short8 af[2], bfr[4];                                                \
      _Pragma("unroll") for (int mf = 0; mf < 2; ++mf) {                   \
        const int row = 32 * w + 16 * mf + fr;                             \
        af[mf] = *(const short8*)&Al[row * 64 +                            \
                 (((kq4 + 4 * c) ^ (row & 7)) << 3)];                      \
      }                                                                    \
      _Pragma("unroll") for (int nf = 0; nf < 4; ++nf) {                   \
        const int row = 16 * nf + fr;                                      \
        bfr[nf] = *(const short8*)&Bl[row * 64 +                           \
                  (((kq4 + 4 * c) ^ (row & 7)) << 3)];                     \
      }                                                                    \
      _Pragma("unroll") for (int mf = 0; mf < 2; ++mf)                     \
      _Pragma("unroll") for (int nf = 0; nf < 4; ++nf)                     \
          mfma16(acc[mf][nf], af[mf], bfr[nf]);                            \
    }                                                                      \
    __syncthreads();                                                       \
  }

// ---------------- plain GEMM: C(MxN) fp32 = A(MxK) * BT(NxK)^T ----------------
__global__ __launch_bounds__(256) void gemm_bt_k(const ushort_t* __restrict__ A,
                                                 const ushort_t* __restrict__ BT,
                                                 float* __restrict__ C,
                                                 int M, int N, int K) {
  __shared__ __align__(16) ushort_t Al[128 * 64];
  __shared__ __align__(16) ushort_t Bl[64 * 64];
  GEMM_PROLOG64();
  GEMM_KLOOP64();
  const int crow = m0 + 32 * w + 4 * (lane >> 4);
  const int ccol = n0 + fr;
#pragma unroll
  for (int mf = 0; mf < 2; ++mf)
#pragma unroll
    for (int nf = 0; nf < 4; ++nf)
#pragma unroll
      for (int r = 0; r < 4; ++r)
        C[(size_t)(crow + 16 * mf + r) * N + ccol + 16 * nf] = acc[mf][nf][r];
}

// ---------- QKV GEMM: fused RoPE + bf16 + head-major, v-head writes Vt direct ----
// Block n-span = 64 = one head: hb = bx%6 (0..3=q, 4=k, 5=v), gg = bx/6.
// v head: acc[mf][nf][r] = qkv[s=crow+16mf+r][d=16nf+fr] -> Vt[g][d][s]:
// 4 consecutive s at fixed d = one ushort4 store; each 128B Vt line is fully
// covered within the block (L2 write-coalesced). Eliminates the vtrans pass.
__global__ __launch_bounds__(256) void gemm_qkv_k(const ushort_t* __restrict__ A,
                                                  const ushort_t* __restrict__ BT,
                                                  const float* __restrict__ cosT,
                                                  const float* __restrict__ sinT,
                                                  ushort_t* __restrict__ Qbf,
                                                  ushort_t* __restrict__ Kbf,
                                                  ushort_t* __restrict__ Vt,
                                                  int M, int N, int K) {
  __shared__ __align__(16) ushort_t Al[128 * 64];
  __shared__ __align__(16) ushort_t Bl[64 * 64];
  GEMM_PROLOG64();
  GEMM_KLOOP64();
  const int crow = m0 + 32 * w + 4 * (lane >> 4);
  const int hb = blockIdx.x % 6;
  const int gg = blockIdx.x / 6;
  if (hb == 5) {  // v head -> Vt[g][d][s] (transposed, direct)
    ushort_t* dst = Vt + (size_t)gg * 64 * 2048;
#pragma unroll
    for (int mf = 0; mf < 2; ++mf)
#pragma unroll
      for (int nf = 0; nf < 4; ++nf) {
        ushort4 o;
        o.x = f2bf(acc[mf][nf][0]);
        o.y = f2bf(acc[mf][nf][1]);
        o.z = f2bf(acc[mf][nf][2]);
        o.w = f2bf(acc[mf][nf][3]);
        *(ushort4*)&dst[(size_t)(16 * nf + fr) * 2048 + crow + 16 * mf] = o;
      }
  } else {        // q or k head: fused RoPE (+ QSCALE for q)
    const float qs = (hb < 4) ? QSCALE : 1.0f;
    ushort_t* dst = (hb < 4) ? Qbf + (size_t)(gg * 4 + hb) * 2048 * 64
                             : Kbf + (size_t)gg * 2048 * 64;
#pragma unroll
    for (int mf = 0; mf < 2; ++mf) {
#pragma unroll
      for (int nf2 = 0; nf2 < 2; ++nf2) {
        const int i = 16 * nf2 + fr;
        float4 cT = *(const float4*)&cosT[(size_t)i * 2048 + crow + 16 * mf];
        float4 sT = *(const float4*)&sinT[(size_t)i * 2048 + crow + 16 * mf];
        const float cc[4] = {cT.x, cT.y, cT.z, cT.w};
        const float ss[4] = {sT.x, sT.y, sT.z, sT.w};
#pragma unroll
        for (int r = 0; r < 4; ++r) {
          const size_t row = crow + 16 * mf + r;
          float x1 = acc[mf][nf2][r], x2 = acc[mf][nf2 + 2][r];
          dst[row * 64 + i]      = f2bf((x1 * cc[r] - x2 * ss[r]) * qs);
          dst[row * 64 + i + 32] = f2bf((x2 * cc[r] + x1 * ss[r]) * qs);
        }
      }
    }
  }
}

// ---------------- bf16 MFMA flash attention v9 (round-10-verified, 44.4 us) ----
// Fixed-max exp2 softmax; ones-MFMA lsum (same bf16 P as PV -> bias cancels);
// swizzled GLDS staging; 4 waves x 16 q-rows; grid 32x32; 4 blocks/CU.
__global__ __launch_bounds__(256, 4) void attn9_k(const ushort_t* __restrict__ Qbf,
                                                  const ushort_t* __restrict__ Kbf,
                                                  const ushort_t* __restrict__ Vt,
                                                  ushort_t* __restrict__ outb) {
  __shared__ __align__(16) ushort_t Kl[2][64 * 64];
  __shared__ __align__(16) ushort_t Vl[2][64 * 64];
  __shared__ __align__(16) ushort_t Pl[4][1024];
  const int gh = blockIdx.x;
  const int y = blockIdx.y;
  const int bb = y & 7, aa = y >> 3;
  const int u = (aa == 0) ? 31 - bb : (aa == 1) ? 16 + bb : (aa == 2) ? 15 - bb : bb;
  const int g = gh >> 2;
  const int w = threadIdx.x >> 6, l = threadIdx.x & 63;
  const int li = l & 15, hi = l >> 4;
  const int q0 = 64 * u + 16 * w;
  const int nt = u + 1;

  const ushort_t* Qh = Qbf + (long)gh * 2048 * 64;
  const ushort_t* Kh = Kbf + (long)g * 2048 * 64;
  const ushort_t* Vh = Vt + (long)g * 64 * 2048;
  char* Pw = (char*)&Pl[w][0];

  const int sr = 16 * w + (l >> 3);
  const int sc = (l & 7) ^ (l >> 3);
  const short8 ones = {0x3F80, 0x3F80, 0x3F80, 0x3F80, 0x3F80, 0x3F80, 0x3F80, 0x3F80};

  short8 aq0 = *(const short8*)&Qh[(q0 + li) * 64 + hi * 8];
  short8 aq1 = *(const short8*)&Qh[(q0 + li) * 64 + 32 + hi * 8];

  f32x4 o[4];
#pragma unroll
  for (int df = 0; df < 4; ++df) o[df] = (f32x4){0.f, 0.f, 0.f, 0.f};
  f32x4 os = (f32x4){0.f, 0.f, 0.f, 0.f};   // row-sums via ones-column MFMA

  // prologue: stage tile 0 into buf 0
  GLDS16(Kh + (long)sr * 64 + sc * 8,         &Kl[0][(16 * w) * 64]);
  GLDS16(Kh + (long)(sr + 8) * 64 + sc * 8,   &Kl[0][(16 * w + 8) * 64]);
  GLDS16(Vh + (long)sr * 2048 + sc * 8,       &Vl[0][(16 * w) * 64]);
  GLDS16(Vh + (long)(sr + 8) * 2048 + sc * 8, &Vl[0][(16 * w + 8) * 64]);
  __syncthreads();

  int buf = 0;
  for (int it = 0; it < nt; ++it) {
    const int t0 = it * 64;
    if (it + 1 < nt) {  // prefetch next tile into buf^1 (stays in flight)
      const int tn = t0 + 64;
      GLDS16(Kh + (long)(tn + sr) * 64 + sc * 8,       &Kl[buf ^ 1][(16 * w) * 64]);
      GLDS16(Kh + (long)(tn + sr + 8) * 64 + sc * 8,   &Kl[buf ^ 1][(16 * w + 8) * 64]);
      GLDS16(Vh + (long)sr * 2048 + tn + sc * 8,       &Vl[buf ^ 1][(16 * w) * 64]);
      GLDS16(Vh + (long)(sr + 8) * 2048 + tn + sc * 8, &Vl[buf ^ 1][(16 * w + 8) * 64]);
    }
    const ushort_t* kb = &Kl[buf][0];
    const ushort_t* vb = &Vl[buf][0];

    // ---- QK^T: S'[16q][64t] (log2 domain) ----
    f32x4 sf[4];
#pragma unroll
    for (int f = 0; f < 4; ++f) sf[f] = (f32x4){0.f, 0.f, 0.f, 0.f};
    __builtin_amdgcn_s_setprio(1);
#pragma unroll
    for (int f = 0; f < 4; ++f) {
      const int row = 16 * f + li;
      short8 b0 = *(const short8*)&kb[row * 64 + ((hi ^ (row & 7)) << 3)];
      short8 b1 = *(const short8*)&kb[row * 64 + (((hi + 4) ^ (row & 7)) << 3)];
      mfma16(sf[f], aq0, b0);
      mfma16(sf[f], aq1, b1);
    }
    __builtin_amdgcn_s_setprio(0);

    // ---- causal mask (diagonal tile only) ----
    if (t0 + 63 > q0) {
#pragma unroll
      for (int f = 0; f < 4; ++f) {
        int t = t0 + 16 * f + li;
#pragma unroll
        for (int r = 0; r < 4; ++r)
          if (t > q0 + 4 * hi + r) sf[f][r] = -1e30f;
      }
    }
    // ---- fixed-max softmax: P = exp2(S' - 12), truncate-store to bf16 ----
#pragma unroll
    for (int f = 0; f < 4; ++f) {
      int k2 = 2 * (li + 16 * f);
#pragma unroll
      for (int r = 0; r < 4; ++r) {
        float p = __builtin_amdgcn_exp2f(sf[f][r] - FIXMAX);
        int q = 4 * hi + r;
        *(ushort_t*)(Pw + q * 128 + (k2 ^ ((q & 7) << 4))) =
            (ushort_t)(__builtin_bit_cast(unsigned, p) >> 16);
      }
    }

    // ---- PV: O[16q][64d] += P * V^T; row-sums accumulate via ones-frag ----
    __builtin_amdgcn_s_setprio(1);
#pragma unroll
    for (int kst = 0; kst < 2; ++kst) {
      short8 pa = *(const short8*)(Pw + li * 128 + (((4 * kst + hi) ^ (li & 7)) << 4));
#pragma unroll
      for (int df = 0; df < 4; ++df) {
        const int row = 16 * df + li;
        short8 bv = *(const short8*)&vb[row * 64 + (((4 * kst + hi) ^ (row & 7)) << 3)];
        mfma16(o[df], pa, bv);
      }
      mfma16(os, pa, ones);
    }
    __builtin_amdgcn_s_setprio(0);

    __syncthreads();  // drains GLDS (vmcnt) + all waves done reading buf
    buf ^= 1;
  }
  // ---- epilogue: normalize by ones-MFMA row-sums, store bf16 (RNE) ----
#pragma unroll
  for (int r = 0; r < 4; ++r) {
    float inv = 1.f / os[r];
#pragma unroll
    for (int df = 0; df < 4; ++df)
      outb[(long)(q0 + 4 * hi + r) * HID_DIM + gh * 64 + 16 * df + li] =
          f2bf(o[df][r] * inv);
  }
}

extern "C" void kernel_launch(void* const* d_in, const int* in_sizes, int n_in,
                              void* d_out, int out_size, void* d_ws, size_t ws_size,
                              hipStream_t stream) {
  const float* X    = (const float*)d_in[0];  // 2048x2048
  const float* cosb = (const float*)d_in[1];  // 2048x32
  const float* sinb = (const float*)d_in[2];  // 2048x32
  const float* Wqkv = (const float*)d_in[3];  // 2048x3072
  const float* Wd   = (const float*)d_in[4];  // 2048x2048
  float* out = (float*)d_out;                 // 2048x2048 fp32

  // workspace (all disjoint, ~49 MB)
  char* ws = (char*)d_ws;
  ushort_t* Xbf   = (ushort_t*)ws;                             // 8 MB
  ushort_t* WqkvT = Xbf + (size_t)2048 * 2048;                 // 12.6 MB
  ushort_t* WdT   = WqkvT + (size_t)3072 * 2048;               // 8 MB
  ushort_t* Qbf   = WdT + (size_t)2048 * 2048;                 // 8 MB
  ushort_t* Kbf   = Qbf + (size_t)32 * 2048 * 64;              // 2 MB
  ushort_t* Vt    = Kbf + (size_t)8 * 2048 * 64;               // 2 MB
  ushort_t* attnO = Vt + (size_t)8 * 2048 * 64;                // 8 MB
  float*    cosT  = (float*)(attnO + (size_t)2048 * 2048);     // 0.25 MB
  float*    sinT  = cosT + (size_t)32 * 2048;                  // 0.25 MB

  // one fused prep launch: cvt(X) | tcvt(Wqkv) | tcvt(Wd) | cs_trans
  prep_k<<<14592, 256, 0, stream>>>(X, Wqkv, Wd, cosb, sinb,
                                    Xbf, WqkvT, WdT, cosT, sinT);

  // qkv GEMM (M=2048, N=3072, K=2048), 128x64 tiles, fused RoPE/bf16 epilogue,
  // v head written directly to Vt (no vtrans pass)
  gemm_qkv_k<<<dim3(3072 / 64, 2048 / 128), 256, 0, stream>>>(
      Xbf, WqkvT, cosT, sinT, Qbf, Kbf, Vt, 2048, 3072, 2048);

  attn9_k<<<dim3(NG * NHQ, 32), 256, 0, stream>>>(Qbf, Kbf, Vt, attnO);

  // out = attnO @ Wd  (M=2048, N=2048, K=2048), 128x64 tiles
  gemm_bt_k<<<dim3(2048 / 64, 2048 / 128), 256, 0, stream>>>(attnO, WdT, out,
                                                             2048, 2048, 2048);
}